// Round 1
// baseline (2115.512 us; speedup 1.0000x reference)
//
#include <hip/hip_runtime.h>
#include <stdint.h>

typedef unsigned long long u64;

#define NB   32      // batch
#define TST  384     // timesteps
#define IDM  64      // input dim
#define HDM  128     // hidden dim
#define NCLS 10
#define EPSF 1e-7f
#define LOG2E 1.44269504088896340736f

// LDS layout (float offsets)
#define O_SBUF 0      // 385 (pad->388)  cached s_buf[t']
#define O_WLDS 388    // 388             attention weights w[t']
#define O_ACT  776    // 192             [x_t(64) | h(128)] activations
#define O_GEX  968    // 512             gate exchange / idx list / fc input
#define O_RED4 1480   // 1024            attn partial reduction (8 waves x 128)
#define O_DELT 2504   // 32              deltas from all batches
#define O_WFC  2536   // 10*264 = 2640   padded W_fc
#define O_BFC  5176   // 12
#define O_MISC 5188   // 32
#define SMTOT  5220

__device__ __forceinline__ float sigm(float x) {
  return 1.0f / (1.0f + __builtin_amdgcn_exp2f(-LOG2E * x));
}
__device__ __forceinline__ float tanh_f(float x) {
  return 1.0f - 2.0f / (1.0f + __builtin_amdgcn_exp2f(2.0f * LOG2E * x));
}

__global__ __launch_bounds__(512, 2)
void sab_kernel(const float* __restrict__ x, const float* __restrict__ Wih,
                const float* __restrict__ Whh, const float* __restrict__ bihp,
                const float* __restrict__ bhhp, const float* __restrict__ wtp,
                const float* __restrict__ Wfcp, const float* __restrict__ bfcp,
                float* __restrict__ dout, u64* __restrict__ mail) {
  __shared__ __align__(16) float SM[SMTOT];
  int* IMISC = (int*)(SM + O_MISC);   // ints at slots 16..23 (counts)
  int* IDX   = (int*)(SM + O_GEX);    // compacted t' indices (reuses GEX)

  const int tid  = threadIdx.x;
  const int lane = tid & 63;
  const int wvid = tid >> 6;
  const int b    = blockIdx.x;
  const int go   = tid >> 3;          // gate octet 0..63
  const int kc   = tid & 7;           // K-chunk 0..7 (24 cols each)

  float* hsout = dout + (size_t)NB * TST * NCLS;     // hs region == attention buf
  const float* myx = x + (size_t)b * TST * IDM;

  // ---- preload weight sub-block: rows 8*go..8*go+7, cols 24*kc..24*kc+23 ----
  float w[8][24];
  #pragma unroll
  for (int i = 0; i < 8; ++i) {
    const int g = 8 * go + i;
    #pragma unroll
    for (int j = 0; j < 24; ++j) {
      const int k = 24 * kc + j;
      const float* sp = (k < IDM) ? (Wih + g * IDM + k) : (Whh + g * HDM + (k - IDM));
      w[i][j] = *sp;
    }
  }
  const float bias = bihp[tid] + bhhp[tid];
  float wt0 = 0.f, wt1 = 0.f, cst = 0.f;
  if (tid < HDM) { wt0 = wtp[tid]; wt1 = wtp[HDM + tid]; }

  // incremental top-5 of s_buf (thread 0 only meaningful); s_buf[0]=0 pre-inserted
  float t5a = 0.f, t5b = -3e38f, t5c = -3e38f, t5d = -3e38f, t5e = -3e38f;

  // ---- init LDS ----
  for (int idx = tid; idx < NCLS * 256; idx += 512) {
    const int c = idx >> 8, k = idx & 255;
    SM[O_WFC + c * 264 + k] = Wfcp[idx];
  }
  if (tid < NCLS) SM[O_BFC + tid] = bfcp[tid];
  if (tid < HDM) SM[O_ACT + 64 + tid] = 0.f;   // h0 = 0
  if (tid < IDM) SM[O_ACT + tid] = myx[tid];   // x_0
  if (tid == 0) {
    SM[O_SBUF] = 0.f;
    __hip_atomic_store(&mail[b],      0ull, __ATOMIC_RELAXED, __HIP_MEMORY_SCOPE_AGENT);
    __hip_atomic_store(&mail[NB + b], 0ull, __ATOMIC_RELAXED, __HIP_MEMORY_SCOPE_AGENT);
  }
  __syncthreads();

  float hc = 0.f;
  for (int t = 0; t < TST; ++t) {
    const int r = t + 1;

    // ================= gates: g = [x|h] @ W^T + bias =================
    float acc[8] = {0,0,0,0,0,0,0,0};
    {
      const float4* a4 = reinterpret_cast<const float4*>(SM + O_ACT + kc * 24);
      #pragma unroll
      for (int m = 0; m < 6; ++m) {
        const float4 av = a4[m];
        #pragma unroll
        for (int i = 0; i < 8; ++i) {
          acc[i] = fmaf(av.x, w[i][4*m+0], acc[i]);
          acc[i] = fmaf(av.y, w[i][4*m+1], acc[i]);
          acc[i] = fmaf(av.z, w[i][4*m+2], acc[i]);
          acc[i] = fmaf(av.w, w[i][4*m+3], acc[i]);
        }
      }
    }
    #pragma unroll
    for (int i = 0; i < 8; ++i) {   // butterfly over the 8 kc lanes
      acc[i] += __shfl_xor(acc[i], 1, 64);
      acc[i] += __shfl_xor(acc[i], 2, 64);
      acc[i] += __shfl_xor(acc[i], 4, 64);
    }
    float pre = acc[0];
    #pragma unroll
    for (int i = 1; i < 8; ++i) if (kc == i) pre = acc[i];  // this thread's gate = tid
    pre += bias;
    const bool tg = (tid >= 256) && (tid < 384);            // gg gates -> tanh
    SM[O_GEX + tid] = tg ? tanh_f(pre) : sigm(pre);
    __syncthreads();                                        // S1

    // ================= LSTM cell (threads 0..127) =================
    float th = 0.f;
    if (tid < HDM) {
      const float iv = SM[O_GEX + tid];
      const float fv = SM[O_GEX + 128 + tid];
      const float gv = SM[O_GEX + 256 + tid];
      const float ov = SM[O_GEX + 384 + tid];
      cst = fv * cst + iv * gv;
      hc  = ov * tanh_f(cst);
      th  = tanh_f(hc) * wt0;        // partial of s_h
    }
    #pragma unroll
    for (int s = 1; s < 64; s <<= 1) th += __shfl_xor(th, s, 64);
    if (lane == 0 && tid < HDM) SM[O_MISC + wvid] = th;
    __syncthreads();                                        // S2
    const float s_h = SM[O_MISC] + SM[O_MISC + 1];

    // ================= delta publish / poll (big branch) =================
    const bool big = (r > 5);
    if (big) {
      if (tid == 0) {
        const float delta = t5e + s_h + EPSF;               // 5th-largest score + eps
        const u64 pv = (((u64)(unsigned)r) << 32) | (u64)__float_as_uint(delta);
        __hip_atomic_store(&mail[(r & 1) * NB + b], pv, __ATOMIC_RELEASE, __HIP_MEMORY_SCOPE_AGENT);
      }
      if (tid < NB) {
        u64* slot = &mail[(r & 1) * NB + tid];
        u64 v = __hip_atomic_load(slot, __ATOMIC_ACQUIRE, __HIP_MEMORY_SCOPE_AGENT);
        while ((unsigned)(v >> 32) != (unsigned)r) {
          __builtin_amdgcn_s_sleep(2);
          v = __hip_atomic_load(slot, __ATOMIC_ACQUIRE, __HIP_MEMORY_SCOPE_AGENT);
        }
        SM[O_DELT + tid] = __uint_as_float((unsigned)v);
      }
    }
    __syncthreads();                                        // S3

    // ================= attention weights =================
    float wval = 0.f;
    bool pred = false;
    if (big) {
      if (tid < r) {
        const int base = (b * r) & (NB - 1);
        const float sc = s_h + SM[O_SBUF + tid];
        wval = fmaxf(sc - SM[O_DELT + ((base + tid) & (NB - 1))], 0.f);
        SM[O_WLDS + tid] = wval;
        pred = (wval > 0.f) && (tid > 0);   // t'=0 row is zeros: no contribution
      }
    } else {
      float scv = (tid < r) ? (s_h + SM[O_SBUF + tid]) : -3e38f;
      float mx = scv;
      #pragma unroll
      for (int s = 1; s < 64; s <<= 1) mx = fmaxf(mx, __shfl_xor(mx, s, 64));
      if (tid < r) {
        wval = __builtin_amdgcn_exp2f(LOG2E * (scv - mx));
        SM[O_WLDS + tid] = wval;
        pred = (tid > 0);
      }
    }
    float wsp = wval;
    #pragma unroll
    for (int s = 1; s < 64; s <<= 1) wsp += __shfl_xor(wsp, s, 64);
    if (lane == 0) SM[O_MISC + 2 + wvid] = wsp;
    const u64 bmask = __ballot((int)pred);
    if (lane == 0) IMISC[16 + wvid] = (int)__popcll(bmask);
    __syncthreads();                                        // S4

    float wsum = 0.f;
    #pragma unroll
    for (int i = 0; i < 8; ++i) wsum += SM[O_MISC + 2 + i];
    const float inv = 1.0f / (wsum + (big ? EPSF : 0.f));
    int wbase = 0, nnz = 0;
    #pragma unroll
    for (int i = 0; i < 8; ++i) {
      const int c = IMISC[16 + i];
      if (i < wvid) wbase += c;
      nnz += c;
    }
    if (pred) {
      const int pos = wbase + (int)__popcll(bmask & ((1ull << lane) - 1ull));
      IDX[pos] = tid;
    }
    __syncthreads();                                        // S5

    // ================= attn_c: sparse gather over buf (== hs rows) =================
    const int j8 = tid & 15, q = tid >> 4;
    float ac[8] = {0,0,0,0,0,0,0,0};
    for (int ii = q; ii < nnz; ii += 32) {
      const int tp = IDX[ii];                                // t' index (>=1)
      const float wgt = SM[O_WLDS + tp] * inv;
      const float* bp = hsout + ((size_t)(b * TST + tp - 1)) * HDM + j8 * 8;
      const float4 v0 = *reinterpret_cast<const float4*>(bp);
      const float4 v1 = *reinterpret_cast<const float4*>(bp + 4);
      ac[0] = fmaf(wgt, v0.x, ac[0]); ac[1] = fmaf(wgt, v0.y, ac[1]);
      ac[2] = fmaf(wgt, v0.z, ac[2]); ac[3] = fmaf(wgt, v0.w, ac[3]);
      ac[4] = fmaf(wgt, v1.x, ac[4]); ac[5] = fmaf(wgt, v1.y, ac[5]);
      ac[6] = fmaf(wgt, v1.z, ac[6]); ac[7] = fmaf(wgt, v1.w, ac[7]);
    }
    #pragma unroll
    for (int i = 0; i < 8; ++i) {     // reduce the 4 q-groups inside each wave
      ac[i] += __shfl_xor(ac[i], 16, 64);
      ac[i] += __shfl_xor(ac[i], 32, 64);
    }
    if ((q & 3) == 0) {
      float4* r4 = reinterpret_cast<float4*>(SM + O_RED4 + wvid * 128 + j8 * 8);
      r4[0] = make_float4(ac[0], ac[1], ac[2], ac[3]);
      r4[1] = make_float4(ac[4], ac[5], ac[6], ac[7]);
    }
    __syncthreads();                                        // S6

    // ================= finalize h, write outputs =================
    float tb = 0.f;
    if (tid < HDM) {
      float s = 0.f;
      #pragma unroll
      for (int wv2 = 0; wv2 < 8; ++wv2) s += SM[O_RED4 + wv2 * 128 + tid];
      const float hf = hc + s;
      hsout[((size_t)(b * TST + t)) * HDM + tid] = hf;
      SM[O_ACT + 64 + tid] = hf;       // h for next step's gates
      SM[O_GEX + tid] = hf;            // FC input [h | attn_c]
      SM[O_GEX + 128 + tid] = s;
      tb = tanh_f(hf) * wt1;           // partial of s_buf[r]
    }
    if (tid < IDM && t + 1 < TST) SM[O_ACT + tid] = myx[(size_t)(t + 1) * IDM + tid];
    #pragma unroll
    for (int s2 = 1; s2 < 64; s2 <<= 1) tb += __shfl_xor(tb, s2, 64);
    if (lane == 0 && tid < HDM) SM[O_MISC + 24 + wvid] = tb;
    __syncthreads();                                        // S7

    if (tid == 0 && r < TST) {
      const float sb = SM[O_MISC + 24] + SM[O_MISC + 25];
      SM[O_SBUF + r] = sb;
      if (sb > t5e) {                  // maintain 5 largest s_buf values
        if (sb > t5a)      { t5e=t5d; t5d=t5c; t5c=t5b; t5b=t5a; t5a=sb; }
        else if (sb > t5b) { t5e=t5d; t5d=t5c; t5c=t5b; t5b=sb; }
        else if (sb > t5c) { t5e=t5d; t5d=t5c; t5c=sb; }
        else if (sb > t5d) { t5e=t5d; t5d=sb; }
        else               { t5e=sb; }
      }
    }
    // ================= fused FC: out = [h|attn_c] @ Wfc^T + bfc =================
    if (tid < 160) {
      const int cls = tid >> 4, p = tid & 15;
      float pt = 0.f;
      #pragma unroll
      for (int i = 0; i < 16; ++i) {
        const int k = p + 16 * i;
        pt = fmaf(SM[O_WFC + cls * 264 + k], SM[O_GEX + k], pt);
      }
      #pragma unroll
      for (int s2 = 1; s2 < 16; s2 <<= 1) pt += __shfl_xor(pt, s2, 64);
      if (p == 0) dout[((size_t)(b * TST + t)) * NCLS + cls] = pt + SM[O_BFC + cls];
    }
    __syncthreads();                                        // loop top
  }
}

extern "C" void kernel_launch(void* const* d_in, const int* in_sizes, int n_in,
                              void* d_out, int out_size, void* d_ws, size_t ws_size,
                              hipStream_t stream) {
  const float* x   = (const float*)d_in[0];
  const float* Wih = (const float*)d_in[1];
  const float* Whh = (const float*)d_in[2];
  const float* bih = (const float*)d_in[3];
  const float* bhh = (const float*)d_in[4];
  const float* wt  = (const float*)d_in[5];
  const float* Wfc = (const float*)d_in[6];
  const float* bfc = (const float*)d_in[7];
  sab_kernel<<<dim3(NB), dim3(512), 0, stream>>>(
      x, Wih, Whh, bih, bhh, wt, Wfc, bfc, (float*)d_out, (u64*)d_ws);
}